// Round 1
// baseline (7220.008 us; speedup 1.0000x reference)
//
#include <hip/hip_runtime.h>

// Order-preserving float -> uint map (for atomicMin/Max on floats).
__device__ __forceinline__ unsigned ford(float f) {
    unsigned u = __float_as_uint(f);
    return (u & 0x80000000u) ? ~u : (u | 0x80000000u);
}
__device__ __forceinline__ float ford_inv(unsigned u) {
    return __uint_as_float((u & 0x80000000u) ? (u & 0x7fffffffu) : ~u);
}

// ws layout (S = num_segments):
//   mnU  : S*3 uint   @ 0
//   mxU  : S*3 uint   @ S*3
//   sum  : S*3 float  @ 2*S*3   (becomes mean after finalize)
//   cnt  : S   float  @ 3*S*3   (becomes 1/(diam+0.01) after finalize)

__global__ void sun_init(unsigned* __restrict__ mnU, unsigned* __restrict__ mxU,
                         float* __restrict__ sum, float* __restrict__ cnt, int S) {
    int t = blockIdx.x * blockDim.x + threadIdx.x;
    int total = S * 3;
    if (t < total) {
        mnU[t] = 0xFF800000u;  // ford(+inf)
        mxU[t] = 0x007FFFFFu;  // ford(-inf)
        sum[t] = 0.0f;
    }
    if (t < S) cnt[t] = 0.0f;
}

__global__ void sun_scatter(const float* __restrict__ pos, const int* __restrict__ idx,
                            unsigned* __restrict__ mnU, unsigned* __restrict__ mxU,
                            float* __restrict__ sum, float* __restrict__ cnt, int N) {
    int stride = gridDim.x * blockDim.x;
    for (int i = blockIdx.x * blockDim.x + threadIdx.x; i < N; i += stride) {
        int s = idx[i];
        float x = pos[3 * i + 0];
        float y = pos[3 * i + 1];
        float z = pos[3 * i + 2];
        int b = 3 * s;
        atomicMin(&mnU[b + 0], ford(x));
        atomicMin(&mnU[b + 1], ford(y));
        atomicMin(&mnU[b + 2], ford(z));
        atomicMax(&mxU[b + 0], ford(x));
        atomicMax(&mxU[b + 1], ford(y));
        atomicMax(&mxU[b + 2], ford(z));
        atomicAdd(&sum[b + 0], x);
        atomicAdd(&sum[b + 1], y);
        atomicAdd(&sum[b + 2], z);
        atomicAdd(&cnt[s], 1.0f);
    }
}

__global__ void sun_finalize(const unsigned* __restrict__ mnU, const unsigned* __restrict__ mxU,
                             float* __restrict__ sum /*-> mean*/, float* __restrict__ cnt /*-> rdiam*/,
                             float* __restrict__ diam_out, int S) {
    int s = blockIdx.x * blockDim.x + threadIdx.x;
    if (s >= S) return;
    int b = 3 * s;
    float c = fmaxf(cnt[s], 1.0f);
    float dx = ford_inv(mxU[b + 0]) - ford_inv(mnU[b + 0]);
    float dy = ford_inv(mxU[b + 1]) - ford_inv(mnU[b + 1]);
    float dz = ford_inv(mxU[b + 2]) - ford_inv(mnU[b + 2]);
    float diam = fmaxf(fmaxf(dx, dy), dz);
    sum[b + 0] = sum[b + 0] / c;
    sum[b + 1] = sum[b + 1] / c;
    sum[b + 2] = sum[b + 2] / c;
    diam_out[s] = diam;
    cnt[s] = 1.0f / (diam + 0.01f);
}

__global__ void sun_gather(const float* __restrict__ pos, const int* __restrict__ idx,
                           const float* __restrict__ mean, const float* __restrict__ rdiam,
                           float* __restrict__ out, int N) {
    int stride = gridDim.x * blockDim.x;
    for (int i = blockIdx.x * blockDim.x + threadIdx.x; i < N; i += stride) {
        int s = idx[i];
        float r = rdiam[s];
        int b = 3 * s;
        out[3 * i + 0] = (pos[3 * i + 0] - mean[b + 0]) * r;
        out[3 * i + 1] = (pos[3 * i + 1] - mean[b + 1]) * r;
        out[3 * i + 2] = (pos[3 * i + 2] - mean[b + 2]) * r;
    }
}

extern "C" void kernel_launch(void* const* d_in, const int* in_sizes, int n_in,
                              void* d_out, int out_size, void* d_ws, size_t ws_size,
                              hipStream_t stream) {
    const float* pos = (const float*)d_in[0];
    const int* idx = (const int*)d_in[1];
    int N = in_sizes[1];                   // 16777216
    int S = out_size - in_sizes[0];        // out_size = N*3 + S

    unsigned* mnU = (unsigned*)d_ws;
    unsigned* mxU = mnU + (size_t)S * 3;
    float* sum = (float*)(mxU + (size_t)S * 3);
    float* cnt = sum + (size_t)S * 3;

    float* out = (float*)d_out;            // [N*3]
    float* diam_out = out + (size_t)N * 3; // [S]

    const int B = 256;
    int initGrid = (S * 3 + B - 1) / B;
    sun_init<<<initGrid, B, 0, stream>>>(mnU, mxU, sum, cnt, S);

    int bigGrid = 2048;  // grid-stride
    sun_scatter<<<bigGrid, B, 0, stream>>>(pos, idx, mnU, mxU, sum, cnt, N);

    int finGrid = (S + B - 1) / B;
    sun_finalize<<<finGrid, B, 0, stream>>>(mnU, mxU, sum, cnt, diam_out, S);

    sun_gather<<<bigGrid, B, 0, stream>>>(pos, idx, sum, cnt, out, N);
}

// Round 4
// 1745.525 us; speedup vs baseline: 4.1363x; 4.1363x over previous
//
#include <hip/hip_runtime.h>

#define SCAN_T 1024
#define SCAN_C 64   /* fast path requires S == SCAN_T * SCAN_C == 65536 */

// Order-preserving float -> uint map (for atomicMin/Max on floats) - fallback path.
__device__ __forceinline__ unsigned ford(float f) {
    unsigned u = __float_as_uint(f);
    if (u & 0x80000000u) return ~u;
    return u | 0x80000000u;
}
__device__ __forceinline__ float ford_inv(unsigned u) {
    if (u & 0x80000000u) return __uint_as_float(u & 0x7fffffffu);
    return __uint_as_float(~u);
}

// ---------------- fast path: counting sort by segment ----------------

__global__ void sun_zero(unsigned* __restrict__ hist, int S) {
    int t = blockIdx.x * blockDim.x + threadIdx.x;
    if (t < S) hist[t] = 0u;
}

__global__ void sun_hist(const int* __restrict__ idx, unsigned* __restrict__ hist, int N) {
    int stride = gridDim.x * blockDim.x;
    for (int i = blockIdx.x * blockDim.x + threadIdx.x; i < N; i += stride) {
        int s = idx[i];
        atomicAdd(&hist[s], 1u);
    }
}

// Single block of SCAN_T threads; each thread serially handles SCAN_C counters.
__global__ void sun_scan(const unsigned* __restrict__ hist, unsigned* __restrict__ offsets,
                         unsigned* __restrict__ cursor, int S, int N) {
    __shared__ unsigned ssum[SCAN_T];
    int t = threadIdx.x;
    int base = t * SCAN_C;
    unsigned acc = 0u;
    for (int j = 0; j < SCAN_C; ++j) acc += hist[base + j];
    ssum[t] = acc;
    __syncthreads();
    for (int off = 1; off < SCAN_T; off <<= 1) {
        unsigned v = 0u;
        if (t >= off) v = ssum[t - off];
        __syncthreads();
        ssum[t] += v;
        __syncthreads();
    }
    unsigned run = 0u;
    if (t > 0) run = ssum[t - 1];
    for (int j = 0; j < SCAN_C; ++j) {
        unsigned c = hist[base + j];
        offsets[base + j] = run;
        cursor[base + j] = run;
        run += c;
    }
    if (t == 0) offsets[S] = (unsigned)N;
}

// Scatter each point's xyz (12B record) into its segment's contiguous slot range.
__global__ void sun_sortscatter(const float* __restrict__ pos, const int* __restrict__ idx,
                                unsigned* __restrict__ cursor, float* __restrict__ recs, int N) {
    int stride = gridDim.x * blockDim.x;
    for (int i = blockIdx.x * blockDim.x + threadIdx.x; i < N; i += stride) {
        int s = idx[i];
        float x = pos[3 * i + 0];
        float y = pos[3 * i + 1];
        float z = pos[3 * i + 2];
        unsigned dst = atomicAdd(&cursor[s], 1u);
        recs[3 * dst + 0] = x;
        recs[3 * dst + 1] = y;
        recs[3 * dst + 2] = z;
    }
}

// One wave (64 lanes) per segment; butterfly reduce in registers, no atomics.
__global__ void sun_segreduce(const float* __restrict__ recs, const unsigned* __restrict__ offsets,
                              float* __restrict__ mean, float* __restrict__ rdiam,
                              float* __restrict__ diam_out, int S) {
    int wid = (blockIdx.x * blockDim.x + threadIdx.x) >> 6;
    int lane = threadIdx.x & 63;
    if (wid >= S) return;
    unsigned start = offsets[wid];
    unsigned end = offsets[wid + 1];
    float inf = __builtin_inff();
    float mnx = inf, mny = inf, mnz = inf;
    float mxx = -inf, mxy = -inf, mxz = -inf;
    float smx = 0.0f, smy = 0.0f, smz = 0.0f;
    for (unsigned i = start + (unsigned)lane; i < end; i += 64u) {
        float x = recs[3 * i + 0];
        float y = recs[3 * i + 1];
        float z = recs[3 * i + 2];
        mnx = fminf(mnx, x); mny = fminf(mny, y); mnz = fminf(mnz, z);
        mxx = fmaxf(mxx, x); mxy = fmaxf(mxy, y); mxz = fmaxf(mxz, z);
        smx += x; smy += y; smz += z;
    }
    for (int m = 1; m < 64; m <<= 1) {
        mnx = fminf(mnx, __shfl_xor(mnx, m));
        mny = fminf(mny, __shfl_xor(mny, m));
        mnz = fminf(mnz, __shfl_xor(mnz, m));
        mxx = fmaxf(mxx, __shfl_xor(mxx, m));
        mxy = fmaxf(mxy, __shfl_xor(mxy, m));
        mxz = fmaxf(mxz, __shfl_xor(mxz, m));
        smx += __shfl_xor(smx, m);
        smy += __shfl_xor(smy, m);
        smz += __shfl_xor(smz, m);
    }
    if (lane == 0) {
        float c = (float)(end - start);
        if (c < 1.0f) c = 1.0f;
        float dx = mxx - mnx;
        float dy = mxy - mny;
        float dz = mxz - mnz;
        float diam = fmaxf(fmaxf(dx, dy), dz);
        mean[3 * wid + 0] = smx / c;
        mean[3 * wid + 1] = smy / c;
        mean[3 * wid + 2] = smz / c;
        diam_out[wid] = diam;
        rdiam[wid] = 1.0f / (diam + 0.01f);
    }
}

__global__ void sun_gather(const float* __restrict__ pos, const int* __restrict__ idx,
                           const float* __restrict__ mean, const float* __restrict__ rdiam,
                           float* __restrict__ out, int N) {
    int stride = gridDim.x * blockDim.x;
    for (int i = blockIdx.x * blockDim.x + threadIdx.x; i < N; i += stride) {
        int s = idx[i];
        float r = rdiam[s];
        int b = 3 * s;
        out[3 * i + 0] = (pos[3 * i + 0] - mean[b + 0]) * r;
        out[3 * i + 1] = (pos[3 * i + 1] - mean[b + 1]) * r;
        out[3 * i + 2] = (pos[3 * i + 2] - mean[b + 2]) * r;
    }
}

// ---------------- fallback path (R1, device atomics) ----------------

__global__ void sun_init(unsigned* __restrict__ mnU, unsigned* __restrict__ mxU,
                         float* __restrict__ sum, float* __restrict__ cnt, int S) {
    int t = blockIdx.x * blockDim.x + threadIdx.x;
    int total = S * 3;
    if (t < total) {
        mnU[t] = 0xFF800000u;
        mxU[t] = 0x007FFFFFu;
        sum[t] = 0.0f;
    }
    if (t < S) cnt[t] = 0.0f;
}

__global__ void sun_scatter(const float* __restrict__ pos, const int* __restrict__ idx,
                            unsigned* __restrict__ mnU, unsigned* __restrict__ mxU,
                            float* __restrict__ sum, float* __restrict__ cnt, int N) {
    int stride = gridDim.x * blockDim.x;
    for (int i = blockIdx.x * blockDim.x + threadIdx.x; i < N; i += stride) {
        int s = idx[i];
        float x = pos[3 * i + 0];
        float y = pos[3 * i + 1];
        float z = pos[3 * i + 2];
        int b = 3 * s;
        atomicMin(&mnU[b + 0], ford(x));
        atomicMin(&mnU[b + 1], ford(y));
        atomicMin(&mnU[b + 2], ford(z));
        atomicMax(&mxU[b + 0], ford(x));
        atomicMax(&mxU[b + 1], ford(y));
        atomicMax(&mxU[b + 2], ford(z));
        atomicAdd(&sum[b + 0], x);
        atomicAdd(&sum[b + 1], y);
        atomicAdd(&sum[b + 2], z);
        atomicAdd(&cnt[s], 1.0f);
    }
}

__global__ void sun_finalize(const unsigned* __restrict__ mnU, const unsigned* __restrict__ mxU,
                             float* __restrict__ sum, float* __restrict__ cnt,
                             float* __restrict__ diam_out, int S) {
    int s = blockIdx.x * blockDim.x + threadIdx.x;
    if (s >= S) return;
    int b = 3 * s;
    float c = fmaxf(cnt[s], 1.0f);
    float dx = ford_inv(mxU[b + 0]) - ford_inv(mnU[b + 0]);
    float dy = ford_inv(mxU[b + 1]) - ford_inv(mnU[b + 1]);
    float dz = ford_inv(mxU[b + 2]) - ford_inv(mnU[b + 2]);
    float diam = fmaxf(fmaxf(dx, dy), dz);
    sum[b + 0] = sum[b + 0] / c;
    sum[b + 1] = sum[b + 1] / c;
    sum[b + 2] = sum[b + 2] / c;
    diam_out[s] = diam;
    cnt[s] = 1.0f / (diam + 0.01f);
}

extern "C" void kernel_launch(void* const* d_in, const int* in_sizes, int n_in,
                              void* d_out, int out_size, void* d_ws, size_t ws_size,
                              hipStream_t stream) {
    const float* pos = (const float*)d_in[0];
    const int* idx = (const int*)d_in[1];
    int N = in_sizes[1];                   // 16777216
    int S = out_size - in_sizes[0];        // out_size = N*3 + S

    float* out = (float*)d_out;            // [N*3]
    float* diam_out = out + (size_t)N * 3; // [S]
    const int B = 256;

    // ws layout (fast path):
    //   recs    : N*3 float
    //   hist    : S uint
    //   offsets : S+1 uint
    //   cursor  : S uint
    //   mean    : S*3 float
    //   rdiam   : S float
    size_t needWs = (size_t)N * 12 + (size_t)S * 4 * 7 + 64;
    bool fast = (S == SCAN_T * SCAN_C) && (ws_size >= needWs);

    if (fast) {
        float* recs = (float*)d_ws;
        unsigned* hist = (unsigned*)(recs + (size_t)N * 3);
        unsigned* offsets = hist + S;
        unsigned* cursor = offsets + S + 1;
        float* mean = (float*)(cursor + S);
        float* rdiam = mean + (size_t)S * 3;

        int zeroGrid = (S + B - 1) / B;
        sun_zero<<<zeroGrid, B, 0, stream>>>(hist, S);
        sun_hist<<<2048, B, 0, stream>>>(idx, hist, N);
        sun_scan<<<1, SCAN_T, 0, stream>>>(hist, offsets, cursor, S, N);
        sun_sortscatter<<<2048, B, 0, stream>>>(pos, idx, cursor, recs, N);
        int redGrid = (S * 64 + B - 1) / B;  // one wave per segment
        sun_segreduce<<<redGrid, B, 0, stream>>>(recs, offsets, mean, rdiam, diam_out, S);
        sun_gather<<<2048, B, 0, stream>>>(pos, idx, mean, rdiam, out, N);
    } else {
        unsigned* mnU = (unsigned*)d_ws;
        unsigned* mxU = mnU + (size_t)S * 3;
        float* sum = (float*)(mxU + (size_t)S * 3);
        float* cnt = sum + (size_t)S * 3;

        int initGrid = (S * 3 + B - 1) / B;
        sun_init<<<initGrid, B, 0, stream>>>(mnU, mxU, sum, cnt, S);
        sun_scatter<<<2048, B, 0, stream>>>(pos, idx, mnU, mxU, sum, cnt, N);
        int finGrid = (S + B - 1) / B;
        sun_finalize<<<finGrid, B, 0, stream>>>(mnU, mxU, sum, cnt, diam_out, S);
        sun_gather<<<2048, B, 0, stream>>>(pos, idx, sum, cnt, out, N);
    }
}